// Round 9
// baseline (4260.460 us; speedup 1.0000x reference)
//
#include <hip/hip_runtime.h>
#include <cmath>

// Sinkhorn distance, B=8, P1=P2=2048, dim=3, EPS=1, MAX_ITER=100, THRESH=1e-9
// Outputs (flat, in return order): cost[8], pi[8*2048*2048], D[8*2048*2048]
//
// Identities:
//  - Entire iteration in log2 domain. Coords pre-scaled by log2(e):
//      d'_ij = |x'_i - y'_j|  (= log2(e) * true distance)
//    Duals kept in log2 space. Weights: log2(1/2048) = -11 exactly.
//      u'_i = -11 - log2( sum_j exp2(v'_j) * exp2(-d'_ij) )
//  - THRESH=1e-9 < f32 ulp of the duals => reference's while_loop can only
//    stop at a bitwise fixed point; R8 measured that none occurs within 100
//    iters => reference runs all 100, and running exactly 100 matches it.
//  - Persistent kernel; cross-wg dual exchange via agent-scope RELAXED
//    atomics only (sc1, IF-coherent, no L2 maintenance). Barrier = vmcnt
//    drain + relaxed fetch_add + relaxed spin. No fences anywhere (R6's
//    __threadfence cost ~24us/phase in L2 maintenance).
//  - Coords staged to LDS once; per-phase duals are read straight from IF
//    into registers (8 x 8B per wave, preloaded), no per-phase LDS staging
//    and no phase-start syncthreads.

constexpr int BATCH = 8;
constexpr int P = 2048;
constexpr int MAX_ITER = 100;
constexpr int WGS_PER_BATCH = 64;            // 32 rows each
constexpr int NWG = BATCH * WGS_PER_BATCH;   // 512 blocks
constexpr int TPB = 1024;                    // 16 waves
constexpr int NPHASE = 2 * MAX_ITER;

#define LOG2E 1.44269504088896340736f
#define LN2   0.69314718055994530942f

typedef __attribute__((ext_vector_type(2))) float v2f;

static __device__ __forceinline__ v2f mkv2(float a, float b) { v2f r; r.x = a; r.y = b; return r; }

// Pack pre-scaled coords into float4, init log2-space duals, zero barrier counters.
__global__ __launch_bounds__(256) void sk_prep(const float* __restrict__ x,
                                               const float* __restrict__ y,
                                               float4* __restrict__ xs,
                                               float4* __restrict__ ys,
                                               float* __restrict__ u,
                                               float* __restrict__ v,
                                               int* __restrict__ cnt)
{
    int idx = blockIdx.x * 256 + threadIdx.x;   // 0 .. BATCH*P-1
    u[idx] = 0.0f;     // log2-space u0 = 0
    v[idx] = -11.0f;   // log2-space v0 = log2(1/2048)
    xs[idx] = make_float4(LOG2E * x[3*idx], LOG2E * x[3*idx+1], LOG2E * x[3*idx+2], 0.f);
    ys[idx] = make_float4(LOG2E * y[3*idx], LOG2E * y[3*idx+1], LOG2E * y[3*idx+2], 0.f);
    if (idx < BATCH * NPHASE) cnt[idx] = 0;     // re-zeroed every call
}

// The whole Sinkhorn loop in one kernel.
// Block: 1024 thr = 16 waves = 8 row-quads x 2 j-halves; 32 output rows/wg.
__global__ __launch_bounds__(TPB, 8) void sk_loop(const float4* __restrict__ xs,
                                                  const float4* __restrict__ ys,
                                                  float* u,
                                                  float* v,
                                                  int* cnt)
{
    __shared__ v2f shx[2][P/2], shy[2][P/2], shz[2][P/2];  // [side][j/2], 48 KiB
    __shared__ float wpart[16][4];

    const int b = blockIdx.x & 7;                   // batch (XCD-local heuristic)
    const int wg = blockIdx.x >> 3;                 // 0..63 within batch
    const int wgrow = wg << 5;                      // this wg's 32-row base
    const int w = threadIdx.x >> 6;
    const int lane = threadIdx.x & 63;
    const int quad = w & 7;                         // row-quad 0..7
    const int half = w >> 3;                        // j half-range
    const int i0 = wgrow + quad * 4;
    const int tbase = half * 512 + lane;            // v2f index into LDS / duals

    const float4* xb = xs + (size_t)b * P;
    const float4* yb = ys + (size_t)b * P;
    float* ub = u + (size_t)b * P;
    float* vb = v + (size_t)b * P;
    int* bar = cnt + b * NPHASE;

    // Stage BOTH coordinate sides into LDS once (read-only thereafter).
    {
        const int t = threadIdx.x;                  // 0..1023 == P/2 entries
        float4 a0 = xb[2*t], a1 = xb[2*t + 1];
        shx[0][t] = mkv2(a0.x, a1.x);
        shy[0][t] = mkv2(a0.y, a1.y);
        shz[0][t] = mkv2(a0.z, a1.z);
        float4 c0 = yb[2*t], c1 = yb[2*t + 1];
        shx[1][t] = mkv2(c0.x, c1.x);
        shy[1][t] = mkv2(c0.y, c1.y);
        shz[1][t] = mkv2(c0.z, c1.z);
    }
    __syncthreads();

    #pragma unroll 1
    for (int it = 0; it < MAX_ITER; ++it) {
        #pragma unroll 1
        for (int ph = 0; ph < 2; ++ph) {
            float* dr = ph ? ub : vb;               // duals being reduced over
            float* dw = ph ? vb : ub;               // duals being written
            const int side = 1 - ph;                // LDS coord side reduced over

            // Preload this wave's 8 dual chunks straight from IF (sc1, relaxed).
            v2f wraw[8];
            #pragma unroll
            for (int k = 0; k < 8; ++k) {
                const int t = tbase + (k << 6);
                unsigned long long q = __hip_atomic_load(
                    (const unsigned long long*)&dr[2*t],
                    __ATOMIC_RELAXED, __HIP_MEMORY_SCOPE_AGENT);
                wraw[k] = __builtin_bit_cast(v2f, q);
            }

            // Own output rows' coords come from LDS (side == ph array).
            float cx[4], cy[4], cz[4];
            {
                const int e0 = i0 >> 1;             // v2f index of rows i0, i0+1
                v2f xa = shx[ph][e0], xbv = shx[ph][e0 + 1];
                v2f ya = shy[ph][e0], ybv = shy[ph][e0 + 1];
                v2f za = shz[ph][e0], zbv = shz[ph][e0 + 1];
                cx[0] = xa.x; cx[1] = xa.y; cx[2] = xbv.x; cx[3] = xbv.y;
                cy[0] = ya.x; cy[1] = ya.y; cy[2] = ybv.x; cy[3] = ybv.y;
                cz[0] = za.x; cz[1] = za.y; cz[2] = zbv.x; cz[3] = zbv.y;
            }

            v2f acc[4];
            #pragma unroll
            for (int r = 0; r < 4; ++r) acc[r] = mkv2(0.f, 0.f);

            const v2f* sx = shx[side];
            const v2f* sy = shy[side];
            const v2f* sz = shz[side];

            #pragma unroll 4
            for (int k = 0; k < 8; ++k) {
                const int t = tbase + (k << 6);
                v2f X = sx[t];
                v2f Y = sy[t];
                v2f Z = sz[t];
                v2f W;
                W.x = __builtin_amdgcn_exp2f(wraw[k].x);
                W.y = __builtin_amdgcn_exp2f(wraw[k].y);
                #pragma unroll
                for (int r = 0; r < 4; ++r) {
                    v2f dx = X - cx[r];                    // v_pk_add_f32 (neg mod)
                    v2f dy = Y - cy[r];
                    v2f dz = Z - cz[r];
                    v2f r2 = dx*dx + dy*dy + dz*dz;        // v_pk_fma_f32 chain
                    v2f e;
                    e.x = __builtin_amdgcn_exp2f(-__builtin_amdgcn_sqrtf(r2.x));
                    e.y = __builtin_amdgcn_exp2f(-__builtin_amdgcn_sqrtf(r2.y));
                    acc[r] += W * e;                       // v_pk_fma_f32
                }
            }

            #pragma unroll
            for (int r = 0; r < 4; ++r) {
                float s = acc[r].x + acc[r].y;
                #pragma unroll
                for (int off = 32; off; off >>= 1) s += __shfl_xor(s, off);
                if (lane == 0) wpart[w][r] = s;
            }
            __syncthreads();

            // combine j-halves; write this wg's 32 duals via sc1 stores (wave 0)
            if (threadIdx.x < 32) {
                const int q = threadIdx.x >> 2;
                const int r = threadIdx.x & 3;
                float s = wpart[q][r] + wpart[q + 8][r];
                float val = -11.0f - __builtin_amdgcn_logf(s);
                __hip_atomic_store(&dw[wgrow + threadIdx.x], val,
                                   __ATOMIC_RELAXED, __HIP_MEMORY_SCOPE_AGENT);
            }

            // per-batch barrier: fence-free (no wbl2/inv). Skip after last phase.
            if (it == MAX_ITER - 1 && ph == 1) continue;
            if (threadIdx.x == 0) {
                const int idx = it * 2 + ph;
                asm volatile("s_waitcnt vmcnt(0)" ::: "memory");  // drain wave-0 dual stores (at IF)
                __hip_atomic_fetch_add(&bar[idx], 1, __ATOMIC_RELAXED, __HIP_MEMORY_SCOPE_AGENT);
                while (__hip_atomic_load(&bar[idx], __ATOMIC_RELAXED,
                                         __HIP_MEMORY_SCOPE_AGENT) != WGS_PER_BATCH)
                    __builtin_amdgcn_s_sleep(2);
            }
            __syncthreads();
        }
    }
}

// Final: D, pi = exp(D + u + v) (faithful to reference's +D sign), rowsum of pi*D.
__global__ __launch_bounds__(256) void sk_final(const float4* __restrict__ xs,
                                                const float4* __restrict__ ys,
                                                const float* __restrict__ u,
                                                const float* __restrict__ v,
                                                float4* __restrict__ outPi,
                                                float4* __restrict__ outD,
                                                float* __restrict__ rowsum)
{
    const int row = blockIdx.x;        // b*P + i
    const int b = row >> 11;

    const float4 a = xs[row];          // scaled x_i
    const float u2 = u[row];           // log2-space u_i
    const float4* vb4 = (const float4*)(v + (size_t)b * P);
    const float4* yb = ys + (size_t)b * P;
    const size_t base4 = (size_t)row * (P / 4);

    float acc = 0.f;
    for (int t = threadIdx.x; t < P / 4; t += 256) {
        float4 dv, pv;
        float4 vv = vb4[t];
        #pragma unroll
        for (int c = 0; c < 4; ++c) {
            int j = 4 * t + c;
            float4 q = yb[j];
            float dx = a.x - q.x;
            float dy = a.y - q.y;
            float dz = a.z - q.z;
            float ds = __builtin_amdgcn_sqrtf(fmaf(dx, dx, fmaf(dy, dy, dz * dz))); // log2e*d
            float d = LN2 * ds;                                        // true distance
            float pi = __builtin_amdgcn_exp2f(ds + u2 + (&vv.x)[c]);   // exp(d+u+v)
            (&dv.x)[c] = d;
            (&pv.x)[c] = pi;
            acc = fmaf(pi, d, acc);
        }
        outD[base4 + t] = dv;
        outPi[base4 + t] = pv;
    }
    #pragma unroll
    for (int off = 32; off; off >>= 1) acc += __shfl_xor(acc, off);
    __shared__ float sred[4];
    if ((threadIdx.x & 63) == 0) sred[threadIdx.x >> 6] = acc;
    __syncthreads();
    if (threadIdx.x == 0) rowsum[row] = sred[0] + sred[1] + sred[2] + sred[3];
}

__global__ __launch_bounds__(256) void sk_cost(const float* __restrict__ rowsum,
                                               float* __restrict__ cost)
{
    const int b = blockIdx.x;
    float acc = 0.f;
    for (int i = threadIdx.x; i < P; i += 256) acc += rowsum[b * P + i];
    #pragma unroll
    for (int off = 32; off; off >>= 1) acc += __shfl_xor(acc, off);
    __shared__ float sred[4];
    if ((threadIdx.x & 63) == 0) sred[threadIdx.x >> 6] = acc;
    __syncthreads();
    if (threadIdx.x == 0) cost[b] = sred[0] + sred[1] + sred[2] + sred[3];
}

extern "C" void kernel_launch(void* const* d_in, const int* in_sizes, int n_in,
                              void* d_out, int out_size, void* d_ws, size_t ws_size,
                              hipStream_t stream)
{
    const float* x = (const float*)d_in[0];
    const float* y = (const float*)d_in[1];

    float* out  = (float*)d_out;
    float* cost = out;                                 // [8]
    float* pi   = out + BATCH;                         // [8*2048*2048]
    float* Dm   = pi + (size_t)BATCH * P * P;          // [8*2048*2048]

    float* u      = (float*)d_ws;                      // [8*2048]  (log2 space)
    float* v      = u + BATCH * P;                     // [8*2048]  (log2 space)
    float* rowsum = v + BATCH * P;                     // [8*2048]
    float4* xs    = (float4*)(rowsum + BATCH * P);     // [8*2048] float4
    float4* ys    = xs + BATCH * P;                    // [8*2048] float4
    int* cnt      = (int*)(ys + BATCH * P);            // [8*200] barrier counters

    sk_prep<<<BATCH * P / 256, 256, 0, stream>>>(x, y, xs, ys, u, v, cnt);

    {
        const float4* xs_c = xs;
        const float4* ys_c = ys;
        float* u_p = u;
        float* v_p = v;
        int* cnt_p = cnt;
        void* args[] = { (void*)&xs_c, (void*)&ys_c, (void*)&u_p, (void*)&v_p, (void*)&cnt_p };
        hipError_t e = hipLaunchCooperativeKernel((const void*)sk_loop,
                                                  dim3(NWG), dim3(TPB),
                                                  args, 0, stream);
        if (e != hipSuccess) {
            // Fallback: plain launch. Grid == exact residency capacity
            // (512 wgs x 16 waves = 8192 waves = 256 CU x 32; LDS 48.1KB -> 2/CU),
            // so all wgs are co-resident by construction.
            sk_loop<<<dim3(NWG), dim3(TPB), 0, stream>>>(xs_c, ys_c, u_p, v_p, cnt_p);
        }
    }

    sk_final<<<BATCH * P, 256, 0, stream>>>(xs, ys, u, v,
                                            (float4*)pi, (float4*)Dm, rowsum);
    sk_cost<<<BATCH, 256, 0, stream>>>(rowsum, cost);
}

// Round 10
// 2364.652 us; speedup vs baseline: 1.8017x; 1.8017x over previous
//
#include <hip/hip_runtime.h>
#include <cmath>

// Sinkhorn distance, B=8, P1=P2=2048, dim=3, EPS=1, MAX_ITER=100, THRESH=1e-9
// Outputs (flat, in return order): cost[8], pi[8*2048*2048], D[8*2048*2048]
//
// Identities:
//  - Entire iteration in log2 domain. Coords pre-scaled by log2(e):
//      d'_ij = |x'_i - y'_j|  (= log2(e) * true distance)
//    Duals kept in log2 space. Weights: log2(1/2048) = -11 exactly.
//      u'_i = -11 - log2( sum_j exp2(v'_j) * exp2(-d'_ij) )
//  - THRESH=1e-9 < f32 ulp of the duals => reference's while_loop can only
//    stop at a bitwise fixed point; R8 measured none occurs in 100 iters
//    => reference runs all 100; we run exactly 100.
//  - Persistent kernel; cross-wg dual exchange via agent-scope RELAXED
//    32-BIT atomics only (plain global_load/store sc1 -> IF-coherent, no L2
//    maintenance, no RMW). NEVER 64-bit atomic loads: R9 measured they
//    lower to RMW atomics -> 10 GB of HBM traffic.
//  - Coords staged to LDS once. Per-phase duals are preloaded straight into
//    REGISTERS (16 x 32-bit sc1 loads per lane, coalesced), so there is no
//    per-phase LDS staging and no phase-start syncthreads; waves run
//    independently between barriers.
//  - Barrier = R7's proven form: leader vmcnt-drain + relaxed fetch_add +
//    relaxed spin + syncthreads. No fences anywhere (R6: __threadfence cost
//    ~24us/phase in L2 maintenance).

constexpr int BATCH = 8;
constexpr int P = 2048;
constexpr int MAX_ITER = 100;
constexpr int WGS_PER_BATCH = 64;            // 32 rows each
constexpr int NWG = BATCH * WGS_PER_BATCH;   // 512 blocks
constexpr int TPB = 1024;                    // 16 waves
constexpr int NPHASE = 2 * MAX_ITER;

#define LOG2E 1.44269504088896340736f
#define LN2   0.69314718055994530942f

typedef __attribute__((ext_vector_type(2))) float v2f;

static __device__ __forceinline__ v2f mkv2(float a, float b) { v2f r; r.x = a; r.y = b; return r; }

// Pack pre-scaled coords into float4, init log2-space duals, zero barrier counters.
__global__ __launch_bounds__(256) void sk_prep(const float* __restrict__ x,
                                               const float* __restrict__ y,
                                               float4* __restrict__ xs,
                                               float4* __restrict__ ys,
                                               float* __restrict__ u,
                                               float* __restrict__ v,
                                               int* __restrict__ cnt)
{
    int idx = blockIdx.x * 256 + threadIdx.x;   // 0 .. BATCH*P-1
    u[idx] = 0.0f;     // log2-space u0 = 0
    v[idx] = -11.0f;   // log2-space v0 = log2(1/2048)
    xs[idx] = make_float4(LOG2E * x[3*idx], LOG2E * x[3*idx+1], LOG2E * x[3*idx+2], 0.f);
    ys[idx] = make_float4(LOG2E * y[3*idx], LOG2E * y[3*idx+1], LOG2E * y[3*idx+2], 0.f);
    if (idx < BATCH * NPHASE) cnt[idx] = 0;     // re-zeroed every call
}

// The whole Sinkhorn loop in one kernel.
// Block: 1024 thr = 16 waves = 8 row-quads x 2 j-halves; 32 output rows/wg.
__global__ __launch_bounds__(TPB, 8) void sk_loop(const float4* __restrict__ xs,
                                                  const float4* __restrict__ ys,
                                                  float* u,
                                                  float* v,
                                                  int* cnt)
{
    __shared__ v2f shx[2][P/2], shy[2][P/2], shz[2][P/2];  // [side][j/2], 48 KiB
    __shared__ float wpart[16][4];

    const int b = blockIdx.x & 7;                   // batch (XCD-local heuristic)
    const int wg = blockIdx.x >> 3;                 // 0..63 within batch
    const int wgrow = wg << 5;                      // this wg's 32-row base
    const int w = threadIdx.x >> 6;
    const int lane = threadIdx.x & 63;
    const int quad = w & 7;                         // row-quad 0..7
    const int half = w >> 3;                        // j half-range
    const int i0 = wgrow + quad * 4;
    const int tbase = half * 512 + lane;            // v2f index into LDS / duals

    const float4* xb = xs + (size_t)b * P;
    const float4* yb = ys + (size_t)b * P;
    float* ub = u + (size_t)b * P;
    float* vb = v + (size_t)b * P;
    int* bar = cnt + b * NPHASE;

    // Stage BOTH coordinate sides into LDS once (read-only thereafter).
    {
        const int t = threadIdx.x;                  // 0..1023 == P/2 entries
        float4 a0 = xb[2*t], a1 = xb[2*t + 1];
        shx[0][t] = mkv2(a0.x, a1.x);
        shy[0][t] = mkv2(a0.y, a1.y);
        shz[0][t] = mkv2(a0.z, a1.z);
        float4 c0 = yb[2*t], c1 = yb[2*t + 1];
        shx[1][t] = mkv2(c0.x, c1.x);
        shy[1][t] = mkv2(c0.y, c1.y);
        shz[1][t] = mkv2(c0.z, c1.z);
    }
    __syncthreads();

    #pragma unroll 1
    for (int it = 0; it < MAX_ITER; ++it) {
        #pragma unroll 1
        for (int ph = 0; ph < 2; ++ph) {
            float* dr = ph ? ub : vb;               // duals being reduced over
            float* dw = ph ? vb : ub;               // duals being written
            const int side = 1 - ph;                // LDS coord side reduced over

            // Preload this wave's dual chunks straight from IF into registers.
            // 32-BIT relaxed atomic loads ONLY (plain sc1 loads, coalesced).
            v2f W[8];
            #pragma unroll
            for (int k = 0; k < 8; ++k) {
                const int t = tbase + (k << 6);
                float d0 = __hip_atomic_load(&dr[2*t],     __ATOMIC_RELAXED, __HIP_MEMORY_SCOPE_AGENT);
                float d1 = __hip_atomic_load(&dr[2*t + 1], __ATOMIC_RELAXED, __HIP_MEMORY_SCOPE_AGENT);
                W[k] = mkv2(d0, d1);
            }
            #pragma unroll
            for (int k = 0; k < 8; ++k) {
                W[k].x = __builtin_amdgcn_exp2f(W[k].x);
                W[k].y = __builtin_amdgcn_exp2f(W[k].y);
            }

            // Own output rows' coords come from LDS (array index == ph).
            float cx[4], cy[4], cz[4];
            {
                const int e0 = i0 >> 1;             // v2f index of rows i0, i0+1
                v2f xa = shx[ph][e0], xbv = shx[ph][e0 + 1];
                v2f ya = shy[ph][e0], ybv = shy[ph][e0 + 1];
                v2f za = shz[ph][e0], zbv = shz[ph][e0 + 1];
                cx[0] = xa.x; cx[1] = xa.y; cx[2] = xbv.x; cx[3] = xbv.y;
                cy[0] = ya.x; cy[1] = ya.y; cy[2] = ybv.x; cy[3] = ybv.y;
                cz[0] = za.x; cz[1] = za.y; cz[2] = zbv.x; cz[3] = zbv.y;
            }

            v2f acc[4];
            #pragma unroll
            for (int r = 0; r < 4; ++r) acc[r] = mkv2(0.f, 0.f);

            const v2f* sx = shx[side];
            const v2f* sy = shy[side];
            const v2f* sz = shz[side];

            #pragma unroll 4
            for (int k = 0; k < 8; ++k) {
                const int t = tbase + (k << 6);
                v2f X = sx[t];
                v2f Y = sy[t];
                v2f Z = sz[t];
                #pragma unroll
                for (int r = 0; r < 4; ++r) {
                    v2f dx = X - cx[r];                    // v_pk_add_f32 (neg mod)
                    v2f dy = Y - cy[r];
                    v2f dz = Z - cz[r];
                    v2f r2 = dx*dx + dy*dy + dz*dz;        // v_pk_fma_f32 chain
                    v2f e;
                    e.x = __builtin_amdgcn_exp2f(-__builtin_amdgcn_sqrtf(r2.x));
                    e.y = __builtin_amdgcn_exp2f(-__builtin_amdgcn_sqrtf(r2.y));
                    acc[r] += W[k] * e;                    // v_pk_fma_f32
                }
            }

            #pragma unroll
            for (int r = 0; r < 4; ++r) {
                float s = acc[r].x + acc[r].y;
                #pragma unroll
                for (int off = 32; off; off >>= 1) s += __shfl_xor(s, off);
                if (lane == 0) wpart[w][r] = s;
            }
            __syncthreads();

            // combine j-halves; write this wg's 32 duals via sc1 stores (wave 0)
            if (threadIdx.x < 32) {
                const int q = threadIdx.x >> 2;
                const int r = threadIdx.x & 3;
                float s = wpart[q][r] + wpart[q + 8][r];
                float val = -11.0f - __builtin_amdgcn_logf(s);
                __hip_atomic_store(&dw[wgrow + threadIdx.x], val,
                                   __ATOMIC_RELAXED, __HIP_MEMORY_SCOPE_AGENT);
            }

            // per-batch barrier: fence-free (no wbl2/inv). Skip after last phase.
            if (it == MAX_ITER - 1 && ph == 1) continue;
            if (threadIdx.x == 0) {
                const int idx = it * 2 + ph;
                asm volatile("s_waitcnt vmcnt(0)" ::: "memory");  // drain wave-0 dual stores (at IF)
                __hip_atomic_fetch_add(&bar[idx], 1, __ATOMIC_RELAXED, __HIP_MEMORY_SCOPE_AGENT);
                while (__hip_atomic_load(&bar[idx], __ATOMIC_RELAXED,
                                         __HIP_MEMORY_SCOPE_AGENT) != WGS_PER_BATCH)
                    __builtin_amdgcn_s_sleep(2);
            }
            __syncthreads();
        }
    }
}

// Final: D, pi = exp(D + u + v) (faithful to reference's +D sign), rowsum of pi*D.
__global__ __launch_bounds__(256) void sk_final(const float4* __restrict__ xs,
                                                const float4* __restrict__ ys,
                                                const float* __restrict__ u,
                                                const float* __restrict__ v,
                                                float4* __restrict__ outPi,
                                                float4* __restrict__ outD,
                                                float* __restrict__ rowsum)
{
    const int row = blockIdx.x;        // b*P + i
    const int b = row >> 11;

    const float4 a = xs[row];          // scaled x_i
    const float u2 = u[row];           // log2-space u_i
    const float4* vb4 = (const float4*)(v + (size_t)b * P);
    const float4* yb = ys + (size_t)b * P;
    const size_t base4 = (size_t)row * (P / 4);

    float acc = 0.f;
    for (int t = threadIdx.x; t < P / 4; t += 256) {
        float4 dv, pv;
        float4 vv = vb4[t];
        #pragma unroll
        for (int c = 0; c < 4; ++c) {
            int j = 4 * t + c;
            float4 q = yb[j];
            float dx = a.x - q.x;
            float dy = a.y - q.y;
            float dz = a.z - q.z;
            float ds = __builtin_amdgcn_sqrtf(fmaf(dx, dx, fmaf(dy, dy, dz * dz))); // log2e*d
            float d = LN2 * ds;                                        // true distance
            float pi = __builtin_amdgcn_exp2f(ds + u2 + (&vv.x)[c]);   // exp(d+u+v)
            (&dv.x)[c] = d;
            (&pv.x)[c] = pi;
            acc = fmaf(pi, d, acc);
        }
        outD[base4 + t] = dv;
        outPi[base4 + t] = pv;
    }
    #pragma unroll
    for (int off = 32; off; off >>= 1) acc += __shfl_xor(acc, off);
    __shared__ float sred[4];
    if ((threadIdx.x & 63) == 0) sred[threadIdx.x >> 6] = acc;
    __syncthreads();
    if (threadIdx.x == 0) rowsum[row] = sred[0] + sred[1] + sred[2] + sred[3];
}

__global__ __launch_bounds__(256) void sk_cost(const float* __restrict__ rowsum,
                                               float* __restrict__ cost)
{
    const int b = blockIdx.x;
    float acc = 0.f;
    for (int i = threadIdx.x; i < P; i += 256) acc += rowsum[b * P + i];
    #pragma unroll
    for (int off = 32; off; off >>= 1) acc += __shfl_xor(acc, off);
    __shared__ float sred[4];
    if ((threadIdx.x & 63) == 0) sred[threadIdx.x >> 6] = acc;
    __syncthreads();
    if (threadIdx.x == 0) cost[b] = sred[0] + sred[1] + sred[2] + sred[3];
}

extern "C" void kernel_launch(void* const* d_in, const int* in_sizes, int n_in,
                              void* d_out, int out_size, void* d_ws, size_t ws_size,
                              hipStream_t stream)
{
    const float* x = (const float*)d_in[0];
    const float* y = (const float*)d_in[1];

    float* out  = (float*)d_out;
    float* cost = out;                                 // [8]
    float* pi   = out + BATCH;                         // [8*2048*2048]
    float* Dm   = pi + (size_t)BATCH * P * P;          // [8*2048*2048]

    float* u      = (float*)d_ws;                      // [8*2048]  (log2 space)
    float* v      = u + BATCH * P;                     // [8*2048]  (log2 space)
    float* rowsum = v + BATCH * P;                     // [8*2048]
    float4* xs    = (float4*)(rowsum + BATCH * P);     // [8*2048] float4
    float4* ys    = xs + BATCH * P;                    // [8*2048] float4
    int* cnt      = (int*)(ys + BATCH * P);            // [8*200] barrier counters

    sk_prep<<<BATCH * P / 256, 256, 0, stream>>>(x, y, xs, ys, u, v, cnt);

    {
        const float4* xs_c = xs;
        const float4* ys_c = ys;
        float* u_p = u;
        float* v_p = v;
        int* cnt_p = cnt;
        void* args[] = { (void*)&xs_c, (void*)&ys_c, (void*)&u_p, (void*)&v_p, (void*)&cnt_p };
        hipError_t e = hipLaunchCooperativeKernel((const void*)sk_loop,
                                                  dim3(NWG), dim3(TPB),
                                                  args, 0, stream);
        if (e != hipSuccess) {
            // Fallback: plain launch. Grid == exact residency capacity
            // (512 wgs x 16 waves = 8192 waves = 256 CU x 32; LDS 48.1KB -> 2/CU),
            // so all wgs are co-resident by construction.
            sk_loop<<<dim3(NWG), dim3(TPB), 0, stream>>>(xs_c, ys_c, u_p, v_p, cnt_p);
        }
    }

    sk_final<<<BATCH * P, 256, 0, stream>>>(xs, ys, u, v,
                                            (float4*)pi, (float4*)Dm, rowsum);
    sk_cost<<<BATCH, 256, 0, stream>>>(rowsum, cost);
}